// Round 4
// baseline (1186701.758 us; speedup 1.0000x reference)
//
#include <hip/hip_runtime.h>

#define T_STEPS 512
#define BATCH   128
#define SDIM    1024
#define ODIM    256
#define NXCD    8
#define NPROD   8                 // g1 producer WGs per XCD-group
#define NG2     2                 // g2 output WGs per XCD-group
#define NROLEX  (NPROD + NG2)     // 10 roles per XCD
#define NROLE   (NXCD * NROLEX)   // 80 working WGs
#define NWG     256               // overprovisioned launch; extras exit after claim
#define NTHR    512               // 8 waves

#define SPIN_LIMIT      (1 << 15) // ~3 ms: bounded spin -> fail-with-counters, never hang
#define SPIN_LIMIT_INIT (1 << 20) // init barrier: more skew tolerance

typedef __attribute__((ext_vector_type(8))) short bf16x8;
typedef __attribute__((ext_vector_type(4))) float f32x4;
typedef __attribute__((ext_vector_type(4))) unsigned int u32x4;
typedef __attribute__((ext_vector_type(2))) unsigned int u32x2;

// ws layout (bytes)
#define WR_OFF   0                          // ushort[1024*1024]  2 MB (w_r bf16)
#define WO_OFF   (2u*1024*1024)             // ushort[256*1024] 512 KB (w_o bf16)
#define TH_OFF   (WO_OFF + 512u*1024)       // 8 g x 4 buf x 16 b x 1024 j bf16 = 1 MB
#define XCTR_OFF (TH_OFF + 1024u*1024)      // 8 XCD claim counters, 64 B apart
#define FLAG_OFF (XCTR_OFF + NXCD*64u)      // 80 role flags, 64 B apart
#define FLAG_STRIDE 16                      // words

// th addressing (ushort units): (g*4+buf)*16384 + b*1024 + j
// Group g == physical XCD g; its th working set (4 bufs x 32 KB) stays resident
// in that XCD's L2; all th/flag steady-state traffic is sc0-only (L2-coherent).

__device__ __forceinline__ unsigned short f2bf(float f) {
    union { float f; unsigned u; } v; v.f = f;
    unsigned r = v.u + 0x7fffu + ((v.u >> 16) & 1u);   // round-to-nearest-even
    return (unsigned short)(r >> 16);
}

// --- XCD-local (sc0, L2-coherent) memory ops ---
#define LOAD16_SC0(d, p, imm) \
    asm volatile("global_load_dwordx4 %0, %1, off offset:" #imm " sc0" \
                 : "=v"(d) : "v"(p))
#define WAIT_HOLD4(a,b,c,d)                                            \
    asm volatile("s_waitcnt vmcnt(0)"                                  \
                 : "+v"(a), "+v"(b), "+v"(c), "+v"(d) :: "memory")
#define STORE8_SC0(p, v) \
    asm volatile("global_store_dwordx2 %0, %1, off sc0" :: "v"(p), "v"(v) : "memory")

__device__ __forceinline__ unsigned ld_flag_x(const unsigned* p) {
    unsigned v;
    asm volatile("global_load_dword %0, %1, off sc0\n\ts_waitcnt vmcnt(0)"
                 : "=v"(v) : "v"(p) : "memory");
    return v;
}
__device__ __forceinline__ void st_flag_x(unsigned* p, unsigned v) {
    asm volatile("global_store_dword %0, %1, off sc0" :: "v"(p), "v"(v) : "memory");
}

// --- device-scope (sc1, cross-XCD) ops: init phase only ---
__device__ __forceinline__ void st_sc1_u16(unsigned short* p, unsigned short v) {
    __hip_atomic_store(p, v, __ATOMIC_RELAXED, __HIP_MEMORY_SCOPE_AGENT);
}
__device__ __forceinline__ unsigned ld_flag_dev(const unsigned* p) {
    return __hip_atomic_load(p, __ATOMIC_RELAXED, __HIP_MEMORY_SCOPE_AGENT);
}
__device__ __forceinline__ void post_flag_dev(unsigned* p, unsigned v) {
    __hip_atomic_store(p, v, __ATOMIC_RELAXED, __HIP_MEMORY_SCOPE_AGENT);
}

__global__ __launch_bounds__(NTHR, 2) void trnn_persistent(
    const float* __restrict__ x, const float* __restrict__ h_init,
    const float* __restrict__ w_r, const float* __restrict__ b_r,
    const float* __restrict__ w_o, const float* __restrict__ b_o,
    float* __restrict__ out, char* __restrict__ ws)
{
    unsigned short* wr_bf = (unsigned short*)(ws + WR_OFF);
    unsigned short* wo_bf = (unsigned short*)(ws + WO_OFF);
    unsigned short* thb   = (unsigned short*)(ws + TH_OFF);
    unsigned*       xctr  = (unsigned*)(ws + XCTR_OFF);
    unsigned*       flags = (unsigned*)(ws + FLAG_OFF);

    // unpadded 16 x 1024 bf16 tile; bank conflicts handled by XOR swizzle
    __shared__ unsigned short lds_th[16 * 1024];   // 32 KB

    const int tid = threadIdx.x;

    // ---- physical XCD id (wave-uniform scalar read; measured 0..7 on MI355X) ----
    unsigned xid;
    asm("s_getreg_b32 %0, hwreg(HW_REG_XCC_ID)" : "=s"(xid));
    xid &= (NXCD - 1);

    // ---- XCD-local role claim: group g == this WG's physical XCD.
    // Resident WGs claim first, so the 10 winners per XCD are guaranteed
    // schedulable -> no residency deadlock; surplus WGs exit. ----
    __shared__ int s_slot;
    if (tid == 0) {
        unsigned sl = __hip_atomic_fetch_add(&xctr[xid * 16], 1u,
                                             __ATOMIC_RELAXED, __HIP_MEMORY_SCOPE_AGENT);
        s_slot = (int)sl;
    }
    __syncthreads();
    const int g = (int)xid, slot = s_slot;
    if (slot >= NROLEX) return;                    // surplus WG: exit
    const int role = g * NROLEX + slot;

    // ---- init: bf16 weights (device-wide, sc1) split across the 80 roles ----
    const int gtid = role * NTHR + tid, gstr = NROLE * NTHR;
    for (int i = gtid; i < SDIM * SDIM; i += gstr) st_sc1_u16(&wr_bf[i], f2bf(w_r[i]));
    for (int i = gtid; i < ODIM * SDIM; i += gstr) st_sc1_u16(&wo_bf[i], f2bf(w_o[i]));

    const int lane = tid & 63;
    const int wv   = tid >> 6;          // wave 0..7
    const int row  = lane & 15;         // batch-within-group (D col)
    const int quad = lane >> 4;
    const int r7   = row & 7;

    const bool is_g1 = (slot < NPROD);
    const int p  = is_g1 ? slot : (slot - NPROD);
    const int jb = p * 128 + wv * 16;   // this wave's j (or o) base
    const int j0 = jb + quad * 4;       // 4 consecutive outputs per thread
    const int gb = g * 16 + row;        // global batch row

    // th_0 (sc0, XCD-local) + h registers
    f32x4 hv = {0.f, 0.f, 0.f, 0.f};
    if (is_g1) {
        hv = *(const f32x4*)&h_init[gb * SDIM + j0];
        u32x2 pk = {(unsigned)f2bf(tanhf(hv[0])) | ((unsigned)f2bf(tanhf(hv[1])) << 16),
                    (unsigned)f2bf(tanhf(hv[2])) | ((unsigned)f2bf(tanhf(hv[3])) << 16)};
        STORE8_SC0(thb + g * 65536 + row * 1024 + j0, pk);
    }

    // ---- global init barrier (device scope, once); publishes th_0 ----
    asm volatile("s_waitcnt vmcnt(0)" ::: "memory");
    __syncthreads();
    if (tid == 0) post_flag_dev(&flags[role * FLAG_STRIDE], 1u);
    if (tid < NROLE) {
        int it = 0;
        while (ld_flag_dev(&flags[tid * FLAG_STRIDE]) < 1u) {
            if (++it > SPIN_LIMIT_INIT) break;     // bounded: fail, don't hang
        }
    }
    __syncthreads();

    // ---- weight-stationary fragments: w[jb+row][k], 128 regs/lane (AGPRs) ----
    const unsigned short* bsrc =
        (is_g1 ? wr_bf : wo_bf) + (jb + row) * SDIM + quad * 8;
    bf16x8 bw[32];
    #pragma unroll
    for (int kk = 0; kk < 32; ++kk) bw[kk] = *(const bf16x8*)(bsrc + kk * 32);

    // staging map: thread (r_st, c0) loads global chunks {c0, c0+32, c0+64, c0+96}
    // (stride 32 chunks = 512 B) and writes them XOR-swizzled: chunk c of row r
    // lands at 32*(c/32) + ((c&31) ^ (r&7)).
    const int r_st = tid >> 5;
    const int c0   = tid & 31;
    const int c0x  = c0 ^ (r_st & 7);
    const unsigned short* sbase = thb + g * 65536 + r_st * 1024 + c0 * 8;
    unsigned short* ldst = &lds_th[r_st * 1024 + c0x * 8];

    // MFMA read: chunk (quad + 4*kk) of row b at swizzled position ^(row&7)
    const unsigned short* arow = &lds_th[row * 1024];
    const int qx8 = (quad ^ (r7 & 3)) * 8;
    const int rb  = r7 >> 2;
    const unsigned short* pe = arow + qx8 + (rb ? 32 : 0);        // even kk
    const unsigned short* po = arow + qx8 + ((rb ^ 1) ? 32 : 0);  // odd kk

    unsigned* myflag = &flags[role * FLAG_STRIDE];

    if (is_g1) {
        const f32x4 brv = *(const f32x4*)&b_r[j0];
        unsigned short* thw = thb + g * 65536 + row * 1024 + j0;

        for (int t = 0; t < T_STEPS; ++t) {
            // poll (sc0, XCD-local L2): 8 peer data flags; lagged g2 anti-dep
            if (tid < NPROD) {
                const unsigned* f = &flags[(g * NROLEX + tid) * FLAG_STRIDE];
                const unsigned tgt = (unsigned)(t + 1);
                int it = 0;
                while (ld_flag_x(f) < tgt) { if (++it > SPIN_LIMIT) break; }
            } else if (tid < NROLEX && t >= 3) {
                const unsigned* f = &flags[(g * NROLEX + tid) * FLAG_STRIDE];
                const unsigned tgt = (unsigned)(t - 1);
                int it = 0;
                while (ld_flag_x(f) < tgt) { if (++it > SPIN_LIMIT) break; }
            }
            __syncthreads();

            // stage th_t tile (sc0 loads, L2-hit) -> swizzled LDS
            const unsigned short* src = sbase + (t & 3) * 16384;
            u32x4 d0, d1, d2, d3;
            LOAD16_SC0(d0, src, 0);
            LOAD16_SC0(d1, src, 512);
            LOAD16_SC0(d2, src, 1024);
            LOAD16_SC0(d3, src, 1536);
            WAIT_HOLD4(d0, d1, d2, d3);
            *(u32x4*)(ldst +   0) = d0;
            *(u32x4*)(ldst + 256) = d1;
            *(u32x4*)(ldst + 512) = d2;
            *(u32x4*)(ldst + 768) = d3;
            __syncthreads();

            // D[j][b] = sum_k w[j][k] th[b][k]
            f32x4 acc = {0.f, 0.f, 0.f, 0.f};
            #pragma unroll
            for (int kk = 0; kk < 32; ++kk) {
                const unsigned short* tp = ((kk & 1) ? po : pe) + (kk >> 1) * 64;
                bf16x8 tf = *(const bf16x8*)tp;
                acc = __builtin_amdgcn_mfma_f32_16x16x32_bf16(bw[kk], tf, acc, 0, 0, 0);
            }

            // h' = 0.75 h + 0.25 (th w_r^T + b_r); publish th' (sc0, one 8 B store)
            f32x4 hn;
            #pragma unroll
            for (int r = 0; r < 4; ++r)
                hn[r] = 0.75f * hv[r] + 0.25f * (acc[r] + brv[r]);
            hv = hn;
            u32x2 pk = {(unsigned)f2bf(tanhf(hn[0])) | ((unsigned)f2bf(tanhf(hn[1])) << 16),
                        (unsigned)f2bf(tanhf(hn[2])) | ((unsigned)f2bf(tanhf(hn[3])) << 16)};
            STORE8_SC0(thw + ((t + 1) & 3) * 16384, pk);

            asm volatile("s_waitcnt vmcnt(0)" ::: "memory");   // drain own stores (L2 ack)
            __syncthreads();                                   // whole WG drained
            if (tid == 0) st_flag_x(myflag, (unsigned)(t + 2));
        }
    } else {
        const f32x4 bov = *(const f32x4*)&b_o[j0];
        if (tid == 0) st_flag_x(myflag, 2u);        // vacuous "staged th_0"

        for (int t = 1; t <= T_STEPS; ++t) {
            const int xbase = (t - 1) * BATCH * ODIM + gb * ODIM + j0;
            const f32x4 xv = *(const f32x4*)&x[xbase];   // overlaps the poll
            if (tid < NPROD) {
                const unsigned* f = &flags[(g * NROLEX + tid) * FLAG_STRIDE];
                const unsigned tgt = (unsigned)(t + 1);
                int it = 0;
                while (ld_flag_x(f) < tgt) { if (++it > SPIN_LIMIT) break; }
            }
            __syncthreads();   // also guards LDS reuse (prev MFMA done)

            const unsigned short* src = sbase + (t & 3) * 16384;
            u32x4 d0, d1, d2, d3;
            LOAD16_SC0(d0, src, 0);
            LOAD16_SC0(d1, src, 512);
            LOAD16_SC0(d2, src, 1024);
            LOAD16_SC0(d3, src, 1536);
            WAIT_HOLD4(d0, d1, d2, d3);
            *(u32x4*)(ldst +   0) = d0;
            *(u32x4*)(ldst + 256) = d1;
            *(u32x4*)(ldst + 512) = d2;
            *(u32x4*)(ldst + 768) = d3;
            __syncthreads();
            // all staged loads drained before the barrier -> safe to release
            if (tid == 0) st_flag_x(myflag, (unsigned)(t + 2));

            f32x4 acc = {0.f, 0.f, 0.f, 0.f};
            #pragma unroll
            for (int kk = 0; kk < 32; ++kk) {
                const unsigned short* tp = ((kk & 1) ? po : pe) + (kk >> 1) * 64;
                bf16x8 tf = *(const bf16x8*)tp;
                acc = __builtin_amdgcn_mfma_f32_16x16x32_bf16(bw[kk], tf, acc, 0, 0, 0);
            }
            f32x4 ov;
            #pragma unroll
            for (int r = 0; r < 4; ++r) ov[r] = acc[r] + bov[r] - xv[r];
            *(f32x4*)&out[xbase] = ov;               // flushed at kernel end
        }
    }
}

extern "C" void kernel_launch(void* const* d_in, const int* in_sizes, int n_in,
                              void* d_out, int out_size, void* d_ws, size_t ws_size,
                              hipStream_t stream) {
    const float* x      = (const float*)d_in[0];
    const float* h_init = (const float*)d_in[1];
    const float* w_r    = (const float*)d_in[2];
    const float* b_r    = (const float*)d_in[3];
    const float* w_o    = (const float*)d_in[4];
    const float* b_o    = (const float*)d_in[5];
    float* out = (float*)d_out;
    char*  ws  = (char*)d_ws;

    // zero XCD claim counters + role flags (ws is poisoned 0xAA before launch)
    (void)hipMemsetAsync(ws + XCTR_OFF, 0, (NXCD + NROLE) * 64, stream);

    trnn_persistent<<<dim3(NWG), dim3(NTHR), 0, stream>>>(
        x, h_init, w_r, b_r, w_o, b_o, out, ws);
}